// Round 6
// baseline (757.433 us; speedup 1.0000x reference)
//
#include <hip/hip_runtime.h>
#include <hip/hip_bf16.h>
#include <math.h>

// Problem constants (fixed-shape problem)
#define NWn 50000   // words
#define NSn 10000   // sentences
#define NEn 100000  // edges
#define Hn  6       // heads
#define DWn 300     // word dim / out channels per head / out cols
#define DSn 640     // sentence dim
#define DHn 2048    // FFN hidden (collapsed away)
#define HCn 1800    // H*C
#define HCp 1824    // H*C padded to multiple of 32 (MFMA K-step)
#define CHUNK 10000 // agg row chunk (5 chunks)
#define ENC_NEGINF 0x007FFFFFu  // enc(-inf)

typedef short bf16x8 __attribute__((ext_vector_type(8)));
typedef float f32x4  __attribute__((ext_vector_type(4)));

__device__ __forceinline__ unsigned enc_ord(float f) {
  unsigned u = __float_as_uint(f);
  return (u & 0x80000000u) ? ~u : (u | 0x80000000u);
}
__device__ __forceinline__ float dec_ord(unsigned u) {
  unsigned v = (u & 0x80000000u) ? (u ^ 0x80000000u) : ~u;
  return __uint_as_float(v);
}
__device__ __forceinline__ float eluf(float x) { return x > 0.0f ? x : expm1f(x); }
__device__ __forceinline__ float b2f(short s) {
  return __uint_as_float(((unsigned)(unsigned short)s) << 16);
}
__device__ __forceinline__ short f2b(float f) {
  __hip_bfloat16 h = __float2bfloat16(f);
  return *(short*)&h;
}

// edge-index loads; flag==1 -> s2w is int64 (read low words), flag==0 -> int32
__device__ __forceinline__ int ld_src(const int* s32, int e, int f) {
  return f ? s32[2 * e] : s32[e];
}
__device__ __forceinline__ int ld_dst(const int* s32, int e, int f) {
  return f ? s32[2 * NEn + 2 * e] : s32[NEn + e];
}

// ---------------- init (ws is poisoned 0xAA; re-init every call) ----------------
__global__ __launch_bounds__(256) void k_init(unsigned* m_enc, float* den, int* deg,
                                              int* cur, int* flag, float* Vs, float* Vd) {
  int i = blockIdx.x * 256 + threadIdx.x;
  if (i < NWn * Hn) { m_enc[i] = ENC_NEGINF; den[i] = 0.0f; }
  if (i < NWn) { deg[i] = 0; cur[i] = 0; }
  if (i < Hn * DSn) Vs[i] = 0.f;
  if (i < Hn * DWn) Vd[i] = 0.f;
  if (i == 0) *flag = 1;
}

// int64 vs int32 probe: for int64 input every odd int32 slot (high word) is 0.
__global__ __launch_bounds__(256) void k_detect(const int* __restrict__ s32, int* flag) {
  int j = threadIdx.x;
  if (s32[2 * j + 1] != 0) atomicAnd(flag, 0);
}

// ---------------- out[row,col] = bc[col] + Hw[row,col]  (GEMM accumulates on top) ----------------
__global__ __launch_bounds__(256) void k_initout(const float* __restrict__ bc,
    const float* __restrict__ Hw, float* __restrict__ outp) {
  int i4 = blockIdx.x * 256 + threadIdx.x;          // 15M/4 float4's, 300/4=75
  if (i4 >= NWn * DWn / 4) return;
  int c4 = (i4 % 75) * 4;
  float4 b = *(const float4*)&bc[c4];
  float4 h = *(const float4*)&Hw[(size_t)i4 * 4];
  float4 o = make_float4(b.x + h.x, b.y + h.y, b.z + h.z, b.w + h.w);
  *(float4*)&outp[(size_t)i4 * 4] = o;
}

// ---------------- fp32 -> bf16 conversion ----------------
__global__ __launch_bounds__(256) void k_cvt(const float* __restrict__ src,
    __hip_bfloat16* __restrict__ dst, int n4) {   // n4 = n/4 (n multiple of 4)
  int i = blockIdx.x * 256 + threadIdx.x;
  if (i >= n4) return;
  float4 v = *(const float4*)&src[(size_t)i * 4];
  __hip_bfloat16 o[4] = {__float2bfloat16(v.x), __float2bfloat16(v.y),
                         __float2bfloat16(v.z), __float2bfloat16(v.w)};
  *(ulong1*)&dst[(size_t)i * 4] = *(ulong1*)o;
}

// ---------------- transpose+convert: W1 [2048,1800] fp32 -> W1t [1800,2048] bf16 ----------------
__global__ __launch_bounds__(256) void k_tcvt(const float* __restrict__ W1,
    __hip_bfloat16* __restrict__ W1t) {
  __shared__ __hip_bfloat16 T[64][65];
  int tid = threadIdx.x;
  int tx = tid & 15, ty = tid >> 4;
  int c0 = blockIdx.x * 64;   // src col base (dst row base)
  int r0 = blockIdx.y * 64;   // src row base (dst col base)
  #pragma unroll
  for (int rr = 0; rr < 4; ++rr) {
    int sr = r0 + rr * 16 + ty;       // always < 2048
    int sc = c0 + tx * 4;
    float4 v;
    if (sc + 3 < HCn) {
      v = *(const float4*)&W1[(size_t)sr * HCn + sc];
    } else {
      v.x = (sc + 0 < HCn) ? W1[(size_t)sr * HCn + sc + 0] : 0.f;
      v.y = (sc + 1 < HCn) ? W1[(size_t)sr * HCn + sc + 1] : 0.f;
      v.z = (sc + 2 < HCn) ? W1[(size_t)sr * HCn + sc + 2] : 0.f;
      v.w = (sc + 3 < HCn) ? W1[(size_t)sr * HCn + sc + 3] : 0.f;
    }
    T[tx * 4 + 0][rr * 16 + ty] = __float2bfloat16(v.x);
    T[tx * 4 + 1][rr * 16 + ty] = __float2bfloat16(v.y);
    T[tx * 4 + 2][rr * 16 + ty] = __float2bfloat16(v.z);
    T[tx * 4 + 3][rr * 16 + ty] = __float2bfloat16(v.w);
  }
  __syncthreads();
  #pragma unroll
  for (int ww = 0; ww < 4; ++ww) {
    int dl = ww * 16 + ty;            // local dst row = src col
    int dr = c0 + dl;
    if (dr >= HCn) continue;
    __hip_bfloat16 o[4] = {T[dl][tx * 4 + 0], T[dl][tx * 4 + 1],
                           T[dl][tx * 4 + 2], T[dl][tx * 4 + 3]};
    *(uint2*)&W1t[(size_t)dr * DHn + r0 + tx * 4] = *(uint2*)o;
  }
}

// ---------------- Vs/Vd with c-split + atomics (zero-init in k_init) ----------------
#define VCC 6   // c-chunks of 50
__global__ __launch_bounds__(256) void k_vsd(const float* __restrict__ Wsrc,
    const float* __restrict__ Wdst, const float* __restrict__ att_src,
    const float* __restrict__ att_dst, float* __restrict__ Vs, float* __restrict__ Vd) {
  int b = blockIdx.x;
  bool isD = b >= Hn * VCC;
  int bb = isD ? b - Hn * VCC : b;
  int h = bb / VCC, cc = bb % VCC;
  int cbeg = h * 300 + cc * 50, cend = cbeg + 50;
  if (!isD) {
    for (int k = threadIdx.x; k < DSn; k += 256) {
      float s = 0.f;
      for (int c = cbeg; c < cend; ++c)
        s = fmaf(att_src[c], Wsrc[(size_t)c * DSn + k], s);
      unsafeAtomicAdd(&Vs[h * DSn + k], s);
    }
  } else {
    for (int k = threadIdx.x; k < DWn; k += 256) {
      float s = 0.f;
      for (int c = cbeg; c < cend; ++c)
        s = fmaf(att_dst[c], Wdst[(size_t)c * DWn + k], s);
      unsafeAtomicAdd(&Vd[h * DWn + k], s);
    }
  }
}

// ---------------- a[row,h] = sum_k X[row,k]*V[h,k]  (wave per row) ----------------
__global__ __launch_bounds__(256) void k_rowdot(const float* __restrict__ X,
    const float* __restrict__ V, float* __restrict__ outv, int nrows, int K) {
  extern __shared__ float VL[];
  for (int i = threadIdx.x; i < Hn * K; i += 256) VL[i] = V[i];
  __syncthreads();
  int row = blockIdx.x * 4 + (threadIdx.x >> 6);
  int lane = threadIdx.x & 63;
  if (row >= nrows) return;
  float acc[Hn] = {0.f, 0.f, 0.f, 0.f, 0.f, 0.f};
  const float* xr = X + (size_t)row * K;
  for (int k = lane; k < K; k += 64) {
    float x = xr[k];
    #pragma unroll
    for (int h = 0; h < Hn; ++h) acc[h] = fmaf(x, VL[h * K + k], acc[h]);
  }
  #pragma unroll
  for (int h = 0; h < Hn; ++h) {
    float v = acc[h];
    for (int ofs = 32; ofs > 0; ofs >>= 1) v += __shfl_down(v, ofs);
    if (lane == 0) outv[(size_t)row * Hn + h] = v;
  }
}

// ---------------- bc[j] = W2[j,:]·b1 + b2[j]  (wave per j) ----------------
__global__ __launch_bounds__(256) void k_bc(const float* __restrict__ W2,
    const float* __restrict__ b1, const float* __restrict__ b2, float* __restrict__ bc) {
  int j = blockIdx.x * 4 + (threadIdx.x >> 6);
  int lane = threadIdx.x & 63;
  if (j >= DWn) return;
  float s = 0.f;
  for (int t = lane; t < DHn; t += 64) s = fmaf(W2[(size_t)j * DHn + t], b1[t], s);
  for (int ofs = 32; ofs > 0; ofs >>= 1) s += __shfl_down(s, ofs);
  if (lane == 0) bc[j] = s + b2[j];
}

// ---------------- MFMA bf16 GEMM: C = A[M,K] @ B[N,K]^T ----------------
// 128x128 tile, BK=32, 4 waves (2x2), 16x16x32 fragments, global_load_lds staging.
// T3 minimum 2-phase: double-buffered LDS; STAGE(t+1) issued after the barrier,
// compute tile t from the other buffer; single __syncthreads per K-step drains
// the in-flight loads AFTER this step's MFMAs issued (load latency hidden).
// Split-K via gridDim.z (K/gridDim.z divisible by 32).
// EPI=0: C bf16 [M,ldc].
// EPI=2: fp32 partial store at Cout + z*M*ldc.
// EPI=3: fp32 unsafeAtomicAdd into Cout rows offset by rowbase (out pre-init'd bc+Hw).
template <int EPI>
__global__ __launch_bounds__(256) void k_mfma(
    const __hip_bfloat16* __restrict__ A, const __hip_bfloat16* __restrict__ B,
    void* __restrict__ Cout, int M, int N, int K, int lda, int ldb, int ldc,
    int rowbase) {
  __shared__ short As[2][128 * 32];
  __shared__ short Bs[2][128 * 32];
  int tid = threadIdx.x, lane = tid & 63, wid = tid >> 6;
  int wr = wid >> 1, wc = wid & 1;
  int m0 = blockIdx.y * 128, n0 = blockIdx.x * 128;
  int z = blockIdx.z;
  int ksp = K / (int)gridDim.z;
  int kbeg = z * ksp;
  int nt = ksp / 32;

  // staging: 8KB/tile = 2 issue-rounds x (4 waves x 64 lanes x 16B)
  auto STAGE = [&](int buf, int kk) {
    #pragma unroll
    for (int i = 0; i < 2; ++i) {
      int slotbase = wid * 128 + i * 64;
      int slot = slotbase + lane;
      int row = slot >> 2, kq = slot & 3;
      int gm = m0 + row; if (gm > M - 1) gm = M - 1;          // clamp, never OOB
      const __hip_bfloat16* gsa = A + (size_t)gm * lda + kk + kq * 8;
      __builtin_amdgcn_global_load_lds(
          (const __attribute__((address_space(1))) void*)gsa,
          (__attribute__((address_space(3))) void*)&As[buf][slotbase * 8], 16, 0, 0);
      int gn = n0 + row; if (gn > N - 1) gn = N - 1;          // clamp
      const __hip_bfloat16* gsb = B + (size_t)gn * ldb + kk + kq * 8;
      __builtin_amdgcn_global_load_lds(
          (const __attribute__((address_space(1))) void*)gsb,
          (__attribute__((address_space(3))) void*)&Bs[buf][slotbase * 8], 16, 0, 0);
    }
  };

  f32x4 acc[4][4] = {};
  STAGE(0, kbeg);
  int cur = 0;
  for (int t = 0; t < nt; ++t) {
    __syncthreads();                       // buf[cur] staged (barrier drains vmcnt)
    if (t + 1 < nt) STAGE(cur ^ 1, kbeg + (t + 1) * 32);   // prefetch next tile
    bf16x8 af[4], bfr[4];
    #pragma unroll
    for (int mf = 0; mf < 4; ++mf)
      af[mf] = *(bf16x8*)&As[cur][(wr * 64 + mf * 16 + (lane & 15)) * 32 + (lane >> 4) * 8];
    #pragma unroll
    for (int nf = 0; nf < 4; ++nf)
      bfr[nf] = *(bf16x8*)&Bs[cur][(wc * 64 + nf * 16 + (lane & 15)) * 32 + (lane >> 4) * 8];
    #pragma unroll
    for (int mf = 0; mf < 4; ++mf)
      #pragma unroll
      for (int nf = 0; nf < 4; ++nf)
        acc[mf][nf] = __builtin_amdgcn_mfma_f32_16x16x32_bf16(af[mf], bfr[nf],
                                                              acc[mf][nf], 0, 0, 0);
    cur ^= 1;
  }
  // store: C/D layout col=lane&15, row=(lane>>4)*4+r  [m89-verified]
  #pragma unroll
  for (int mf = 0; mf < 4; ++mf) {
    int gmb = m0 + wr * 64 + mf * 16 + (lane >> 4) * 4;
    #pragma unroll
    for (int nf = 0; nf < 4; ++nf) {
      int gn = n0 + wc * 64 + nf * 16 + (lane & 15);
      if (gn >= N) continue;
      #pragma unroll
      for (int r = 0; r < 4; ++r) {
        int gm = gmb + r;
        if (gm >= M) continue;
        if (EPI == 0) {
          ((__hip_bfloat16*)Cout)[(size_t)gm * ldc + gn] = __float2bfloat16(acc[mf][nf][r]);
        } else if (EPI == 2) {
          ((float*)Cout)[((size_t)z * M + gm) * ldc + gn] = acc[mf][nf][r];
        } else {
          size_t grow = (size_t)(rowbase + gm);
          unsafeAtomicAdd(&((float*)Cout)[grow * ldc + gn], acc[mf][nf][r]);
        }
      }
    }
  }
}

// ---------------- reduce split-K partials -> Wcb bf16 (zero K-pad cols) ----------------
__global__ __launch_bounds__(256) void k_wc_reduce(const float* __restrict__ part,
    __hip_bfloat16* __restrict__ Wcb) {
  int i = blockIdx.x * 256 + threadIdx.x;
  if (i >= DWn * HCp) return;
  int m = i / HCp, n = i % HCp;
  float s = 0.f;
  if (n < HCn) {
    #pragma unroll
    for (int s8 = 0; s8 < 8; ++s8)
      s += part[((size_t)s8 * DWn + m) * HCp + n];
  }
  Wcb[i] = __float2bfloat16(s);
}

// ---------------- edge phase ----------------
__global__ __launch_bounds__(256) void k_alpha(const int* __restrict__ s32,
    const int* __restrict__ flag, const float* __restrict__ a_s,
    const float* __restrict__ a_d, float* __restrict__ alpha,
    unsigned* __restrict__ m_enc, int* __restrict__ deg) {
  int e = blockIdx.x * 256 + threadIdx.x;
  if (e >= NEn) return;
  int f = *flag;
  int s = ld_src(s32, e, f), d = ld_dst(s32, e, f);
  atomicAdd(&deg[d], 1);
  #pragma unroll
  for (int h = 0; h < Hn; ++h) {
    float av = a_s[s * Hn + h] + a_d[d * Hn + h];
    float lr = av > 0.f ? av : 0.2f * av;
    alpha[(size_t)e * Hn + h] = lr;
    atomicMax(&m_enc[d * Hn + h], enc_ord(lr));
  }
}

// in-place: wgt buffer holds alpha on input, exp(alpha - m) on output
__global__ __launch_bounds__(256) void k_ex(const int* __restrict__ s32,
    const int* __restrict__ flag, float* __restrict__ wgt,
    const unsigned* __restrict__ m_enc, float* __restrict__ den) {
  int e = blockIdx.x * 256 + threadIdx.x;
  if (e >= NEn) return;
  int d = ld_dst(s32, e, *flag);
  #pragma unroll
  for (int h = 0; h < Hn; ++h) {
    float mx = dec_ord(m_enc[d * Hn + h]);
    float exv = expf(wgt[(size_t)e * Hn + h] - mx);
    wgt[(size_t)e * Hn + h] = exv;
    unsafeAtomicAdd(&den[d * Hn + h], exv);
  }
}

// ---------------- 2-level exclusive scan of deg[NW] -> off[NW] ----------------
__global__ __launch_bounds__(256) void k_scan1(const int* __restrict__ deg,
    int* __restrict__ off, int* __restrict__ bsum) {
  __shared__ int sh[256];
  int i = blockIdx.x * 256 + threadIdx.x;
  int v = (i < NWn) ? deg[i] : 0;
  sh[threadIdx.x] = v;
  __syncthreads();
  for (int ofs = 1; ofs < 256; ofs <<= 1) {
    int t = (threadIdx.x >= ofs) ? sh[threadIdx.x - ofs] : 0;
    __syncthreads();
    sh[threadIdx.x] += t;
    __syncthreads();
  }
  if (i < NWn) off[i] = sh[threadIdx.x] - v;
  if (threadIdx.x == 255) bsum[blockIdx.x] = sh[255];
}

__global__ __launch_bounds__(256) void k_scan2(const int* __restrict__ bsum,
    int* __restrict__ boff, int nb) {
  __shared__ int sh[256];
  int v = (threadIdx.x < nb) ? bsum[threadIdx.x] : 0;
  sh[threadIdx.x] = v;
  __syncthreads();
  for (int ofs = 1; ofs < 256; ofs <<= 1) {
    int t = (threadIdx.x >= ofs) ? sh[threadIdx.x - ofs] : 0;
    __syncthreads();
    sh[threadIdx.x] += t;
    __syncthreads();
  }
  if (threadIdx.x < nb) boff[threadIdx.x] = sh[threadIdx.x] - v;
}

__global__ __launch_bounds__(256) void k_scan3(int* __restrict__ off,
    const int* __restrict__ boff) {
  int i = blockIdx.x * 256 + threadIdx.x;
  if (i < NWn) off[i] += boff[blockIdx.x];
}

__global__ __launch_bounds__(256) void k_fill(const int* __restrict__ s32,
    const int* __restrict__ flag, const int* __restrict__ off,
    int* __restrict__ cur, int* __restrict__ eid) {
  int e = blockIdx.x * 256 + threadIdx.x;
  if (e >= NEn) return;
  int d = ld_dst(s32, e, *flag);
  int pos = off[d] + atomicAdd(&cur[d], 1);
  eid[pos] = e;
}

// ---------------- aggc = elu(softmax-weighted sum + bias) -> bf16, K-padded ----------------
// one block per dst row; thread t owns cols [t*8, t*8+8)  (1800 = 225*8 exactly)
__global__ __launch_bounds__(256) void k_agg(const int* __restrict__ s32,
    const int* __restrict__ flag, const int* __restrict__ eid,
    const int* __restrict__ off, const __hip_bfloat16* __restrict__ xs,
    const float* __restrict__ wgt, const float* __restrict__ den,
    const float* __restrict__ bias_gat, __hip_bfloat16* __restrict__ aggc,
    int rowbase) {
  int d = rowbase + blockIdx.x;
  int c0 = threadIdx.x * 8;
  if (c0 >= HCp) return;
  if (c0 >= HCn) {                         // K-pad cols: zero
    bf16x8 zz = {};
    *(bf16x8*)&aggc[(size_t)blockIdx.x * HCp + c0] = zz;
    return;
  }
  int f = *flag;
  int start = off[d];
  int end = (d == NWn - 1) ? NEn : off[d + 1];
  int hlo = c0 / 300, hhi = (c0 + 7) / 300;
  int split = (hlo == hhi) ? 8 : (hhi * 300 - c0);
  float acc[8] = {};
  for (int p = start; p < end; ++p) {
    int e = eid[p];
    int s = ld_src(s32, e, f);
    bf16x8 x = *(const bf16x8*)&xs[(size_t)s * HCn + c0];
    float wlo = wgt[(size_t)e * Hn + hlo];
    float whi = wgt[(size_t)e * Hn + hhi];
    #pragma unroll
    for (int j = 0; j < 8; ++j)
      acc[j] = fmaf((j < split) ? wlo : whi, b2f(x[j]), acc[j]);
  }
  float dlo = den[(size_t)d * Hn + hlo];
  float dhi = den[(size_t)d * Hn + hhi];
  float ilo = dlo > 0.f ? 1.0f / dlo : 0.f;
  float ihi = dhi > 0.f ? 1.0f / dhi : 0.f;
  float4 b0 = *(const float4*)&bias_gat[c0];
  float4 b1v = *(const float4*)&bias_gat[c0 + 4];
  float bb[8] = {b0.x, b0.y, b0.z, b0.w, b1v.x, b1v.y, b1v.z, b1v.w};
  bf16x8 o;
  #pragma unroll
  for (int j = 0; j < 8; ++j)
    o[j] = f2b(eluf(acc[j] * ((j < split) ? ilo : ihi) + bb[j]));
  *(bf16x8*)&aggc[(size_t)blockIdx.x * HCp + c0] = o;
}

// ---------------- launch ----------------
extern "C" void kernel_launch(void* const* d_in, const int* in_sizes, int n_in,
                              void* d_out, int out_size, void* d_ws, size_t ws_size,
                              hipStream_t stream) {
  const float* Hw       = (const float*)d_in[0];
  const float* Hs       = (const float*)d_in[1];
  const int*   s2w      = (const int*)d_in[2];
  const float* Wsrc     = (const float*)d_in[3];
  const float* Wdst     = (const float*)d_in[4];
  const float* att_src  = (const float*)d_in[5];
  const float* att_dst  = (const float*)d_in[6];
  const float* bias_gat = (const float*)d_in[7];
  const float* W1       = (const float*)d_in[8];
  const float* b1       = (const float*)d_in[9];
  const float* W2       = (const float*)d_in[10];
  const float* b2       = (const float*)d_in[11];
  float* out = (float*)d_out;

  char* ws = (char*)d_ws;
  size_t o = 0;
  auto alloc = [&](size_t bytes) {
    size_t cur = o;
    o = (o + bytes + 255) & ~(size_t)255;
    return cur;
  };
  __hip_bfloat16* xs    = (__hip_bfloat16*)(ws + alloc(2ull * NSn * HCn));      // 36 MB
  __hip_bfloat16* Hsb   = (__hip_bfloat16*)(ws + alloc(2ull * NSn * DSn));      // 12.8 MB
  __hip_bfloat16* Wsrcb = (__hip_bfloat16*)(ws + alloc(2ull * HCn * DSn));      // 2.3 MB
  __hip_bfloat16* aggc  = (__hip_bfloat16*)(ws + alloc(2ull * CHUNK * HCp));    // 36.5 MB
  __hip_bfloat16* Wcb   = (__hip_bfloat16*)(ws + alloc(2ull * DWn * HCp));      // 1.1 MB
  __hip_bfloat16* W2b   = (__hip_bfloat16*)(ws + alloc(2ull * DWn * DHn));      // 1.2 MB
  __hip_bfloat16* W1t   = (__hip_bfloat16*)(ws + alloc(2ull * HCn * DHn));      // 7.4 MB
  float*    WcP   = (float*)(ws + alloc(4ull * 8 * DWn * HCp));                 // 17.5 MB
  float*    bc    = (float*)(ws + alloc(sizeof(float) * DWn));
  float*    Vs    = (float*)(ws + alloc(sizeof(float) * Hn * DSn));
  float*    Vd    = (float*)(ws + alloc(sizeof(float) * Hn * DWn));
  float*    a_s   = (float*)(ws + alloc(sizeof(float) * (size_t)NSn * Hn));
  float*    a_d   = (float*)(ws + alloc(sizeof(float) * (size_t)NWn * Hn));
  float*    wgt   = (float*)(ws + alloc(sizeof(float) * (size_t)NEn * Hn));  // alpha then exp
  unsigned* m_enc = (unsigned*)(ws + alloc(sizeof(unsigned) * (size_t)NWn * Hn));
  float*    den   = (float*)(ws + alloc(sizeof(float) * (size_t)NWn * Hn));
  int*      deg   = (int*)(ws + alloc(sizeof(int) * NWn));
  int*      offr  = (int*)(ws + alloc(sizeof(int) * NWn));
  int*      cur   = (int*)(ws + alloc(sizeof(int) * NWn));
  int*      eid   = (int*)(ws + alloc(sizeof(int) * NEn));
  int*      bsum  = (int*)(ws + alloc(sizeof(int) * 256));
  int*      boff  = (int*)(ws + alloc(sizeof(int) * 256));
  int*      flag  = (int*)(ws + alloc(sizeof(int) * 64));
  (void)in_sizes; (void)n_in; (void)out_size;
  if (o > ws_size) return;  // refuse to scribble past the workspace

  const int NWB = (NWn + 255) / 256;  // 196

  // 1. init
  k_init<<<dim3((NWn * Hn + 255) / 256), dim3(256), 0, stream>>>(
      m_enc, den, deg, cur, flag, Vs, Vd);
  // 2. int64/int32 edge-index probe
  k_detect<<<dim3(1), dim3(256), 0, stream>>>(s2w, flag);
  // 3. bf16 conversions: Hs, Wsrc, W2; transpose-convert W1
  k_cvt<<<dim3((NSn * DSn / 4 + 255) / 256), dim3(256), 0, stream>>>(Hs, Hsb, NSn * DSn / 4);
  k_cvt<<<dim3((HCn * DSn / 4 + 255) / 256), dim3(256), 0, stream>>>(Wsrc, Wsrcb, HCn * DSn / 4);
  k_cvt<<<dim3((DWn * DHn / 4 + 255) / 256), dim3(256), 0, stream>>>(W2, W2b, DWn * DHn / 4);
  k_tcvt<<<dim3((HCn + 63) / 64, DHn / 64), dim3(256), 0, stream>>>(W1, W1t);
  // 4. Vs, Vd (c-split atomics)
  k_vsd<<<dim3(2 * Hn * VCC), dim3(256), 0, stream>>>(
      Wsrc, Wdst, att_src, att_dst, Vs, Vd);
  // 5. bc = W2@b1 + b2, then out = bc + Hw (final GEMM accumulates on top)
  k_bc<<<dim3((DWn + 3) / 4), dim3(256), 0, stream>>>(W2, b1, b2, bc);
  k_initout<<<dim3((NWn * DWn / 4 + 255) / 256), dim3(256), 0, stream>>>(bc, Hw, out);
  // 6. Wc = W2b @ W1t^T via split-K MFMA (M=300, N=1800, K=2048, 8 splits)
  k_mfma<2><<<dim3((HCn + 127) / 128, (DWn + 127) / 128, 8), dim3(256), 0, stream>>>(
      W2b, W1t, WcP, DWn, HCn, DHn, DHn, DHn, HCp, 0);
  k_wc_reduce<<<dim3((DWn * HCp + 255) / 256), dim3(256), 0, stream>>>(WcP, Wcb);
  // 7. a_s = Hs @ Vs^T, a_d = Hw @ Vd^T
  k_rowdot<<<dim3((NSn + 3) / 4), dim3(256), Hn * DSn * sizeof(float), stream>>>(
      Hs, Vs, a_s, NSn, DSn);
  k_rowdot<<<dim3((NWn + 3) / 4), dim3(256), Hn * DWn * sizeof(float), stream>>>(
      Hw, Vd, a_d, NWn, DWn);
  // 8. xs = Hsb @ Wsrcb^T -> bf16  (M=10000, N=1800, K=640) via MFMA
  k_mfma<0><<<dim3((HCn + 127) / 128, (NSn + 127) / 128, 1), dim3(256), 0, stream>>>(
      Hsb, Wsrcb, xs, NSn, HCn, DSn, DSn, DSn, HCn, 0);
  // 9. per-edge alpha + segment max + degree
  k_alpha<<<dim3((NEn + 255) / 256), dim3(256), 0, stream>>>(
      s2w, flag, a_s, a_d, wgt, m_enc, deg);
  // 10. per-edge exp + segment sum (in-place on wgt)
  k_ex<<<dim3((NEn + 255) / 256), dim3(256), 0, stream>>>(s2w, flag, wgt, m_enc, den);
  // 11. CSR build
  k_scan1<<<dim3(NWB), dim3(256), 0, stream>>>(deg, offr, bsum);
  k_scan2<<<dim3(1), dim3(256), 0, stream>>>(bsum, boff, NWB);
  k_scan3<<<dim3(NWB), dim3(256), 0, stream>>>(offr, boff);
  k_fill<<<dim3((NEn + 255) / 256), dim3(256), 0, stream>>>(s2w, flag, offr, cur, eid);
  // 12. chunked: aggregate (+bias+elu -> bf16) then split-K MFMA atomic-accumulating
  //     into out (z=3, ksp=608=19*32)
  for (int c = 0; c < NWn / CHUNK; ++c) {
    int rowbase = c * CHUNK;
    k_agg<<<dim3(CHUNK), dim3(256), 0, stream>>>(
        s2w, flag, eid, offr, xs, wgt, den, bias_gat, aggc, rowbase);
    k_mfma<3><<<dim3((DWn + 127) / 128, (CHUNK + 127) / 128, 3), dim3(256), 0, stream>>>(
        aggc, Wcb, out, CHUNK, DWn, HCp, HCp, HCp, DWn, rowbase);
  }
}

// Round 7
// 568.282 us; speedup vs baseline: 1.3328x; 1.3328x over previous
//
#include <hip/hip_runtime.h>
#include <hip/hip_bf16.h>
#include <math.h>

// Problem constants (fixed-shape problem)
#define NWn 50000   // words
#define NSn 10000   // sentences
#define NEn 100000  // edges
#define Hn  6       // heads
#define DWn 300     // word dim / out channels per head / out cols
#define DSn 640     // sentence dim
#define DHn 2048    // FFN hidden (collapsed away)
#define HCn 1800    // H*C
#define HCp 1824    // H*C padded to multiple of 32 (MFMA K-step)
#define CHUNK 10000 // agg row chunk (5 chunks, fallback path)
#define ENC_NEGINF 0x007FFFFFu  // enc(-inf)

typedef short bf16x8 __attribute__((ext_vector_type(8)));
typedef float f32x4  __attribute__((ext_vector_type(4)));

__device__ __forceinline__ unsigned enc_ord(float f) {
  unsigned u = __float_as_uint(f);
  return (u & 0x80000000u) ? ~u : (u | 0x80000000u);
}
__device__ __forceinline__ float dec_ord(unsigned u) {
  unsigned v = (u & 0x80000000u) ? (u ^ 0x80000000u) : ~u;
  return __uint_as_float(v);
}
__device__ __forceinline__ float eluf(float x) { return x > 0.0f ? x : expm1f(x); }
__device__ __forceinline__ float b2f(short s) {
  return __uint_as_float(((unsigned)(unsigned short)s) << 16);
}
__device__ __forceinline__ short f2b(float f) {
  __hip_bfloat16 h = __float2bfloat16(f);
  return *(short*)&h;
}

// edge-index loads; flag==1 -> s2w is int64 (read low words), flag==0 -> int32
__device__ __forceinline__ int ld_src(const int* s32, int e, int f) {
  return f ? s32[2 * e] : s32[e];
}
__device__ __forceinline__ int ld_dst(const int* s32, int e, int f) {
  return f ? s32[2 * NEn + 2 * e] : s32[NEn + e];
}

// ---------------- init (ws is poisoned 0xAA; re-init every call) ----------------
__global__ __launch_bounds__(256) void k_init(unsigned* m_enc, float* den, int* deg,
                                              int* cur, int* flag, float* Vs, float* Vd) {
  int i = blockIdx.x * 256 + threadIdx.x;
  if (i < NWn * Hn) { m_enc[i] = ENC_NEGINF; den[i] = 0.0f; }
  if (i < NWn) { deg[i] = 0; cur[i] = 0; }
  if (i < Hn * DSn) Vs[i] = 0.f;
  if (i < Hn * DWn) Vd[i] = 0.f;
  if (i == 0) *flag = 1;
}

// int64 vs int32 probe: for int64 input every odd int32 slot (high word) is 0.
__global__ __launch_bounds__(256) void k_detect(const int* __restrict__ s32, int* flag) {
  int j = threadIdx.x;
  if (s32[2 * j + 1] != 0) atomicAnd(flag, 0);
}

// ---------------- out[row,col] = bc[col] + Hw[row,col]  (fallback path only) ----------------
__global__ __launch_bounds__(256) void k_initout(const float* __restrict__ bc,
    const float* __restrict__ Hw, float* __restrict__ outp) {
  int i4 = blockIdx.x * 256 + threadIdx.x;          // 15M/4 float4's, 300/4=75
  if (i4 >= NWn * DWn / 4) return;
  int c4 = (i4 % 75) * 4;
  float4 b = *(const float4*)&bc[c4];
  float4 h = *(const float4*)&Hw[(size_t)i4 * 4];
  float4 o = make_float4(b.x + h.x, b.y + h.y, b.z + h.z, b.w + h.w);
  *(float4*)&outp[(size_t)i4 * 4] = o;
}

// ---------------- fp32 -> bf16 conversion ----------------
__global__ __launch_bounds__(256) void k_cvt(const float* __restrict__ src,
    __hip_bfloat16* __restrict__ dst, int n4) {   // n4 = n/4 (n multiple of 4)
  int i = blockIdx.x * 256 + threadIdx.x;
  if (i >= n4) return;
  float4 v = *(const float4*)&src[(size_t)i * 4];
  __hip_bfloat16 o[4] = {__float2bfloat16(v.x), __float2bfloat16(v.y),
                         __float2bfloat16(v.z), __float2bfloat16(v.w)};
  *(ulong1*)&dst[(size_t)i * 4] = *(ulong1*)o;
}

// ---------------- transpose+convert: W1 [2048,1800] fp32 -> W1t [1800,2048] bf16 ----------------
__global__ __launch_bounds__(256) void k_tcvt(const float* __restrict__ W1,
    __hip_bfloat16* __restrict__ W1t) {
  __shared__ __hip_bfloat16 T[64][65];
  int tid = threadIdx.x;
  int tx = tid & 15, ty = tid >> 4;
  int c0 = blockIdx.x * 64;   // src col base (dst row base)
  int r0 = blockIdx.y * 64;   // src row base (dst col base)
  #pragma unroll
  for (int rr = 0; rr < 4; ++rr) {
    int sr = r0 + rr * 16 + ty;       // always < 2048
    int sc = c0 + tx * 4;
    float4 v;
    if (sc + 3 < HCn) {
      v = *(const float4*)&W1[(size_t)sr * HCn + sc];
    } else {
      v.x = (sc + 0 < HCn) ? W1[(size_t)sr * HCn + sc + 0] : 0.f;
      v.y = (sc + 1 < HCn) ? W1[(size_t)sr * HCn + sc + 1] : 0.f;
      v.z = (sc + 2 < HCn) ? W1[(size_t)sr * HCn + sc + 2] : 0.f;
      v.w = (sc + 3 < HCn) ? W1[(size_t)sr * HCn + sc + 3] : 0.f;
    }
    T[tx * 4 + 0][rr * 16 + ty] = __float2bfloat16(v.x);
    T[tx * 4 + 1][rr * 16 + ty] = __float2bfloat16(v.y);
    T[tx * 4 + 2][rr * 16 + ty] = __float2bfloat16(v.z);
    T[tx * 4 + 3][rr * 16 + ty] = __float2bfloat16(v.w);
  }
  __syncthreads();
  #pragma unroll
  for (int ww = 0; ww < 4; ++ww) {
    int dl = ww * 16 + ty;            // local dst row = src col
    int dr = c0 + dl;
    if (dr >= HCn) continue;
    __hip_bfloat16 o[4] = {T[dl][tx * 4 + 0], T[dl][tx * 4 + 1],
                           T[dl][tx * 4 + 2], T[dl][tx * 4 + 3]};
    *(uint2*)&W1t[(size_t)dr * DHn + r0 + tx * 4] = *(uint2*)o;
  }
}

// ---------------- Vs/Vd with c-split + atomics (zero-init in k_init) ----------------
#define VCC 6   // c-chunks of 50
__global__ __launch_bounds__(256) void k_vsd(const float* __restrict__ Wsrc,
    const float* __restrict__ Wdst, const float* __restrict__ att_src,
    const float* __restrict__ att_dst, float* __restrict__ Vs, float* __restrict__ Vd) {
  int b = blockIdx.x;
  bool isD = b >= Hn * VCC;
  int bb = isD ? b - Hn * VCC : b;
  int h = bb / VCC, cc = bb % VCC;
  int cbeg = h * 300 + cc * 50, cend = cbeg + 50;
  if (!isD) {
    for (int k = threadIdx.x; k < DSn; k += 256) {
      float s = 0.f;
      for (int c = cbeg; c < cend; ++c)
        s = fmaf(att_src[c], Wsrc[(size_t)c * DSn + k], s);
      unsafeAtomicAdd(&Vs[h * DSn + k], s);
    }
  } else {
    for (int k = threadIdx.x; k < DWn; k += 256) {
      float s = 0.f;
      for (int c = cbeg; c < cend; ++c)
        s = fmaf(att_dst[c], Wdst[(size_t)c * DWn + k], s);
      unsafeAtomicAdd(&Vd[h * DWn + k], s);
    }
  }
}

// ---------------- a[row,h] = sum_k X[row,k]*V[h,k]  (wave per row) ----------------
__global__ __launch_bounds__(256) void k_rowdot(const float* __restrict__ X,
    const float* __restrict__ V, float* __restrict__ outv, int nrows, int K) {
  extern __shared__ float VL[];
  for (int i = threadIdx.x; i < Hn * K; i += 256) VL[i] = V[i];
  __syncthreads();
  int row = blockIdx.x * 4 + (threadIdx.x >> 6);
  int lane = threadIdx.x & 63;
  if (row >= nrows) return;
  float acc[Hn] = {0.f, 0.f, 0.f, 0.f, 0.f, 0.f};
  const float* xr = X + (size_t)row * K;
  for (int k = lane; k < K; k += 64) {
    float x = xr[k];
    #pragma unroll
    for (int h = 0; h < Hn; ++h) acc[h] = fmaf(x, VL[h * K + k], acc[h]);
  }
  #pragma unroll
  for (int h = 0; h < Hn; ++h) {
    float v = acc[h];
    for (int ofs = 32; ofs > 0; ofs >>= 1) v += __shfl_down(v, ofs);
    if (lane == 0) outv[(size_t)row * Hn + h] = v;
  }
}

// ---------------- bc[j] = W2[j,:]·b1 + b2[j]  (wave per j) ----------------
__global__ __launch_bounds__(256) void k_bc(const float* __restrict__ W2,
    const float* __restrict__ b1, const float* __restrict__ b2, float* __restrict__ bc) {
  int j = blockIdx.x * 4 + (threadIdx.x >> 6);
  int lane = threadIdx.x & 63;
  if (j >= DWn) return;
  float s = 0.f;
  for (int t = lane; t < DHn; t += 64) s = fmaf(W2[(size_t)j * DHn + t], b1[t], s);
  for (int ofs = 32; ofs > 0; ofs >>= 1) s += __shfl_down(s, ofs);
  if (lane == 0) bc[j] = s + b2[j];
}

// ---------------- MFMA bf16 GEMM: C = A[M,K] @ B[N,K]^T ----------------
// 128x128 tile, BK=32, 4 waves (2x2), 16x16x32 fragments, global_load_lds staging,
// double-buffered LDS, bijective XCD swizzle (m204) over the x-y grid.
// EPI=0: C bf16 [M,ldc].
// EPI=1: C fp32 = acc + bc[col] + Hw[row,col] (direct store, rows offset rowbase).
// EPI=2: fp32 partial store at Cout + z*M*ldc.
// EPI=3: fp32 unsafeAtomicAdd into Cout rows offset rowbase (out pre-init'd bc+Hw).
template <int EPI>
__global__ __launch_bounds__(256) void k_mfma(
    const __hip_bfloat16* __restrict__ A, const __hip_bfloat16* __restrict__ B,
    void* __restrict__ Cout, int M, int N, int K, int lda, int ldb, int ldc,
    const float* __restrict__ bc, const float* __restrict__ Hw, int rowbase) {
  __shared__ short As[2][128 * 32];
  __shared__ short Bs[2][128 * 32];
  int tid = threadIdx.x, lane = tid & 63, wid = tid >> 6;
  int wr = wid >> 1, wc = wid & 1;
  // bijective XCD swizzle (m204): swz-contiguous chunks land on one XCD's L2
  int nwg = (int)(gridDim.x * gridDim.y);
  int wg = (int)(blockIdx.y * gridDim.x + blockIdx.x);
  int q = nwg >> 3, r = nwg & 7;
  int xcd = wg & 7, idx = wg >> 3;
  int swz = (xcd < r) ? (xcd * (q + 1) + idx) : (r * (q + 1) + (xcd - r) * q + idx);
  int m0 = (swz / (int)gridDim.x) * 128, n0 = (swz % (int)gridDim.x) * 128;
  int z = blockIdx.z;
  int ksp = K / (int)gridDim.z;
  int kbeg = z * ksp;
  int nt = ksp / 32;

  // staging: 8KB/tile = 2 issue-rounds x (4 waves x 64 lanes x 16B)
  auto STAGE = [&](int buf, int kk) {
    #pragma unroll
    for (int i = 0; i < 2; ++i) {
      int slotbase = wid * 128 + i * 64;
      int slot = slotbase + lane;
      int row = slot >> 2, kq = slot & 3;
      int gm = m0 + row; if (gm > M - 1) gm = M - 1;          // clamp, never OOB
      const __hip_bfloat16* gsa = A + (size_t)gm * lda + kk + kq * 8;
      __builtin_amdgcn_global_load_lds(
          (const __attribute__((address_space(1))) void*)gsa,
          (__attribute__((address_space(3))) void*)&As[buf][slotbase * 8], 16, 0, 0);
      int gn = n0 + row; if (gn > N - 1) gn = N - 1;          // clamp
      const __hip_bfloat16* gsb = B + (size_t)gn * ldb + kk + kq * 8;
      __builtin_amdgcn_global_load_lds(
          (const __attribute__((address_space(1))) void*)gsb,
          (__attribute__((address_space(3))) void*)&Bs[buf][slotbase * 8], 16, 0, 0);
    }
  };

  f32x4 acc[4][4] = {};
  STAGE(0, kbeg);
  int cur = 0;
  for (int t = 0; t < nt; ++t) {
    __syncthreads();                       // buf[cur] staged (barrier drains vmcnt)
    if (t + 1 < nt) STAGE(cur ^ 1, kbeg + (t + 1) * 32);   // prefetch next tile
    bf16x8 af[4], bfr[4];
    #pragma unroll
    for (int mf = 0; mf < 4; ++mf)
      af[mf] = *(bf16x8*)&As[cur][(wr * 64 + mf * 16 + (lane & 15)) * 32 + (lane >> 4) * 8];
    #pragma unroll
    for (int nf = 0; nf < 4; ++nf)
      bfr[nf] = *(bf16x8*)&Bs[cur][(wc * 64 + nf * 16 + (lane & 15)) * 32 + (lane >> 4) * 8];
    #pragma unroll
    for (int mf = 0; mf < 4; ++mf)
      #pragma unroll
      for (int nf = 0; nf < 4; ++nf)
        acc[mf][nf] = __builtin_amdgcn_mfma_f32_16x16x32_bf16(af[mf], bfr[nf],
                                                              acc[mf][nf], 0, 0, 0);
    cur ^= 1;
  }
  // store: C/D layout col=lane&15, row=(lane>>4)*4+r  [m89-verified]
  #pragma unroll
  for (int mf = 0; mf < 4; ++mf) {
    int gmb = m0 + wr * 64 + mf * 16 + (lane >> 4) * 4;
    #pragma unroll
    for (int nf = 0; nf < 4; ++nf) {
      int gn = n0 + wc * 64 + nf * 16 + (lane & 15);
      if (gn >= N) continue;
      #pragma unroll
      for (int r4 = 0; r4 < 4; ++r4) {
        int gm = gmb + r4;
        if (gm >= M) continue;
        if (EPI == 0) {
          ((__hip_bfloat16*)Cout)[(size_t)gm * ldc + gn] = __float2bfloat16(acc[mf][nf][r4]);
        } else if (EPI == 1) {
          size_t grow = (size_t)(rowbase + gm);
          ((float*)Cout)[grow * ldc + gn] = acc[mf][nf][r4] + bc[gn] + Hw[grow * ldc + gn];
        } else if (EPI == 2) {
          ((float*)Cout)[((size_t)z * M + gm) * ldc + gn] = acc[mf][nf][r4];
        } else {
          size_t grow = (size_t)(rowbase + gm);
          unsafeAtomicAdd(&((float*)Cout)[grow * ldc + gn], acc[mf][nf][r4]);
        }
      }
    }
  }
}

// ---------------- reduce split-K partials -> Wcb bf16 (zero K-pad cols) ----------------
__global__ __launch_bounds__(256) void k_wc_reduce(const float* __restrict__ part,
    __hip_bfloat16* __restrict__ Wcb) {
  int i = blockIdx.x * 256 + threadIdx.x;
  if (i >= DWn * HCp) return;
  int m = i / HCp, n = i % HCp;
  float s = 0.f;
  if (n < HCn) {
    #pragma unroll
    for (int s8 = 0; s8 < 8; ++s8)
      s += part[((size_t)s8 * DWn + m) * HCp + n];
  }
  Wcb[i] = __float2bfloat16(s);
}

// ---------------- edge phase ----------------
__global__ __launch_bounds__(256) void k_alpha(const int* __restrict__ s32,
    const int* __restrict__ flag, const float* __restrict__ a_s,
    const float* __restrict__ a_d, float* __restrict__ alpha,
    unsigned* __restrict__ m_enc, int* __restrict__ deg) {
  int e = blockIdx.x * 256 + threadIdx.x;
  if (e >= NEn) return;
  int f = *flag;
  int s = ld_src(s32, e, f), d = ld_dst(s32, e, f);
  atomicAdd(&deg[d], 1);
  #pragma unroll
  for (int h = 0; h < Hn; ++h) {
    float av = a_s[s * Hn + h] + a_d[d * Hn + h];
    float lr = av > 0.f ? av : 0.2f * av;
    alpha[(size_t)e * Hn + h] = lr;
    atomicMax(&m_enc[d * Hn + h], enc_ord(lr));
  }
}

// in-place: wgt buffer holds alpha on input, exp(alpha - m) on output
__global__ __launch_bounds__(256) void k_ex(const int* __restrict__ s32,
    const int* __restrict__ flag, float* __restrict__ wgt,
    const unsigned* __restrict__ m_enc, float* __restrict__ den) {
  int e = blockIdx.x * 256 + threadIdx.x;
  if (e >= NEn) return;
  int d = ld_dst(s32, e, *flag);
  #pragma unroll
  for (int h = 0; h < Hn; ++h) {
    float mx = dec_ord(m_enc[d * Hn + h]);
    float exv = expf(wgt[(size_t)e * Hn + h] - mx);
    wgt[(size_t)e * Hn + h] = exv;
    unsafeAtomicAdd(&den[d * Hn + h], exv);
  }
}

// ---------------- 2-level exclusive scan of deg[NW] -> off[NW] ----------------
__global__ __launch_bounds__(256) void k_scan1(const int* __restrict__ deg,
    int* __restrict__ off, int* __restrict__ bsum) {
  __shared__ int sh[256];
  int i = blockIdx.x * 256 + threadIdx.x;
  int v = (i < NWn) ? deg[i] : 0;
  sh[threadIdx.x] = v;
  __syncthreads();
  for (int ofs = 1; ofs < 256; ofs <<= 1) {
    int t = (threadIdx.x >= ofs) ? sh[threadIdx.x - ofs] : 0;
    __syncthreads();
    sh[threadIdx.x] += t;
    __syncthreads();
  }
  if (i < NWn) off[i] = sh[threadIdx.x] - v;
  if (threadIdx.x == 255) bsum[blockIdx.x] = sh[255];
}

__global__ __launch_bounds__(256) void k_scan2(const int* __restrict__ bsum,
    int* __restrict__ boff, int nb) {
  __shared__ int sh[256];
  int v = (threadIdx.x < nb) ? bsum[threadIdx.x] : 0;
  sh[threadIdx.x] = v;
  __syncthreads();
  for (int ofs = 1; ofs < 256; ofs <<= 1) {
    int t = (threadIdx.x >= ofs) ? sh[threadIdx.x - ofs] : 0;
    __syncthreads();
    sh[threadIdx.x] += t;
    __syncthreads();
  }
  if (threadIdx.x < nb) boff[threadIdx.x] = sh[threadIdx.x] - v;
}

__global__ __launch_bounds__(256) void k_scan3(int* __restrict__ off,
    const int* __restrict__ boff) {
  int i = blockIdx.x * 256 + threadIdx.x;
  if (i < NWn) off[i] += boff[blockIdx.x];
}

__global__ __launch_bounds__(256) void k_fill(const int* __restrict__ s32,
    const int* __restrict__ flag, const int* __restrict__ off,
    int* __restrict__ cur, int* __restrict__ eid) {
  int e = blockIdx.x * 256 + threadIdx.x;
  if (e >= NEn) return;
  int d = ld_dst(s32, e, *flag);
  int pos = off[d] + atomicAdd(&cur[d], 1);
  eid[pos] = e;
}

// ---------------- aggc = elu(softmax-weighted sum + bias) -> bf16, K-padded ----------------
// one block per dst row; thread t owns cols [t*8, t*8+8)  (1800 = 225*8 exactly)
__global__ __launch_bounds__(256) void k_agg(const int* __restrict__ s32,
    const int* __restrict__ flag, const int* __restrict__ eid,
    const int* __restrict__ off, const __hip_bfloat16* __restrict__ xs,
    const float* __restrict__ wgt, const float* __restrict__ den,
    const float* __restrict__ bias_gat, __hip_bfloat16* __restrict__ aggc,
    int rowbase) {
  int d = rowbase + blockIdx.x;
  int c0 = threadIdx.x * 8;
  if (c0 >= HCp) return;
  if (c0 >= HCn) {                         // K-pad cols: zero
    bf16x8 zz = {};
    *(bf16x8*)&aggc[(size_t)blockIdx.x * HCp + c0] = zz;
    return;
  }
  int f = *flag;
  int start = off[d];
  int end = (d == NWn - 1) ? NEn : off[d + 1];
  int hlo = c0 / 300, hhi = (c0 + 7) / 300;
  int split = (hlo == hhi) ? 8 : (hhi * 300 - c0);
  float acc[8] = {};
  for (int p = start; p < end; ++p) {
    int e = eid[p];
    int s = ld_src(s32, e, f);
    bf16x8 x = *(const bf16x8*)&xs[(size_t)s * HCn + c0];
    float wlo = wgt[(size_t)e * Hn + hlo];
    float whi = wgt[(size_t)e * Hn + hhi];
    #pragma unroll
    for (int j = 0; j < 8; ++j)
      acc[j] = fmaf((j < split) ? wlo : whi, b2f(x[j]), acc[j]);
  }
  float dlo = den[(size_t)d * Hn + hlo];
  float dhi = den[(size_t)d * Hn + hhi];
  float ilo = dlo > 0.f ? 1.0f / dlo : 0.f;
  float ihi = dhi > 0.f ? 1.0f / dhi : 0.f;
  float4 b0 = *(const float4*)&bias_gat[c0];
  float4 b1v = *(const float4*)&bias_gat[c0 + 4];
  float bb[8] = {b0.x, b0.y, b0.z, b0.w, b1v.x, b1v.y, b1v.z, b1v.w};
  bf16x8 o;
  #pragma unroll
  for (int j = 0; j < 8; ++j)
    o[j] = f2b(eluf(acc[j] * ((j < split) ? ilo : ihi) + bb[j]));
  *(bf16x8*)&aggc[(size_t)blockIdx.x * HCp + c0] = o;
}

// ---------------- launch ----------------
extern "C" void kernel_launch(void* const* d_in, const int* in_sizes, int n_in,
                              void* d_out, int out_size, void* d_ws, size_t ws_size,
                              hipStream_t stream) {
  const float* Hw       = (const float*)d_in[0];
  const float* Hs       = (const float*)d_in[1];
  const int*   s2w      = (const int*)d_in[2];
  const float* Wsrc     = (const float*)d_in[3];
  const float* Wdst     = (const float*)d_in[4];
  const float* att_src  = (const float*)d_in[5];
  const float* att_dst  = (const float*)d_in[6];
  const float* bias_gat = (const float*)d_in[7];
  const float* W1       = (const float*)d_in[8];
  const float* b1       = (const float*)d_in[9];
  const float* W2       = (const float*)d_in[10];
  const float* b2       = (const float*)d_in[11];
  float* out = (float*)d_out;

  char* ws = (char*)d_ws;
  size_t o = 0;
  auto alloc = [&](size_t bytes) {
    size_t cur = o;
    o = (o + bytes + 255) & ~(size_t)255;
    return cur;
  };
  // ---- always-live buffers (~44 MB) ----
  __hip_bfloat16* xs    = (__hip_bfloat16*)(ws + alloc(2ull * NSn * HCn));      // 36 MB
  __hip_bfloat16* Wsrcb = (__hip_bfloat16*)(ws + alloc(2ull * HCn * DSn));      // 2.3 MB
  __hip_bfloat16* Wcb   = (__hip_bfloat16*)(ws + alloc(2ull * DWn * HCp));      // 1.1 MB
  float*    bc    = (float*)(ws + alloc(sizeof(float) * DWn));
  float*    Vs    = (float*)(ws + alloc(sizeof(float) * Hn * DSn));
  float*    Vd    = (float*)(ws + alloc(sizeof(float) * Hn * DWn));
  float*    a_s   = (float*)(ws + alloc(sizeof(float) * (size_t)NSn * Hn));
  float*    a_d   = (float*)(ws + alloc(sizeof(float) * (size_t)NWn * Hn));
  float*    wgt   = (float*)(ws + alloc(sizeof(float) * (size_t)NEn * Hn));  // alpha then exp
  unsigned* m_enc = (unsigned*)(ws + alloc(sizeof(unsigned) * (size_t)NWn * Hn));
  float*    den   = (float*)(ws + alloc(sizeof(float) * (size_t)NWn * Hn));
  int*      deg   = (int*)(ws + alloc(sizeof(int) * NWn));
  int*      offr  = (int*)(ws + alloc(sizeof(int) * NWn));
  int*      cur   = (int*)(ws + alloc(sizeof(int) * NWn));
  int*      eid   = (int*)(ws + alloc(sizeof(int) * NEn));
  int*      bsum  = (int*)(ws + alloc(sizeof(int) * 256));
  int*      boff  = (int*)(ws + alloc(sizeof(int) * 256));
  int*      flag  = (int*)(ws + alloc(sizeof(int) * 64));
  // ---- union region: Hsb/W2b/W1t/WcP (dead after step 8) aliased under aggc_full ----
  size_t region = o;
  size_t ro = region;
  auto ralloc = [&](size_t bytes) {
    size_t cur2 = ro;
    ro = (ro + bytes + 255) & ~(size_t)255;
    return cur2;
  };
  __hip_bfloat16* Hsb = (__hip_bfloat16*)(ws + ralloc(2ull * NSn * DSn));       // 12.8 MB
  __hip_bfloat16* W2b = (__hip_bfloat16*)(ws + ralloc(2ull * DWn * DHn));       // 1.2 MB
  __hip_bfloat16* W1t = (__hip_bfloat16*)(ws + ralloc(2ull * HCn * DHn));       // 7.4 MB
  float*          WcP = (float*)(ws + ralloc(4ull * 8 * DWn * HCp));            // 17.5 MB
  size_t region_small_end = ro;
  size_t big_end = region + 2ull * NWn * HCp;          // aggc_full = 182.4 MB
  bool bigpath = (big_end <= ws_size);
  __hip_bfloat16* aggc;
  if (bigpath) {
    aggc = (__hip_bfloat16*)(ws + region);   // overlays Hsb/W2b/W1t/WcP (dead by step 12)
  } else {
    o = region_small_end;
    aggc = (__hip_bfloat16*)(ws + alloc(2ull * CHUNK * HCp));                   // 36.5 MB
    if (o > ws_size) return;  // refuse to scribble past the workspace
  }
  (void)in_sizes; (void)n_in; (void)out_size;

  const int NWB = (NWn + 255) / 256;  // 196

  // 1. init
  k_init<<<dim3((NWn * Hn + 255) / 256), dim3(256), 0, stream>>>(
      m_enc, den, deg, cur, flag, Vs, Vd);
  // 2. int64/int32 edge-index probe
  k_detect<<<dim3(1), dim3(256), 0, stream>>>(s2w, flag);
  // 3. bf16 conversions: Hs, Wsrc, W2; transpose-convert W1
  k_cvt<<<dim3((NSn * DSn / 4 + 255) / 256), dim3(256), 0, stream>>>(Hs, Hsb, NSn * DSn / 4);
  k_cvt<<<dim3((HCn * DSn / 4 + 255) / 256), dim3(256), 0, stream>>>(Wsrc, Wsrcb, HCn * DSn / 4);
  k_cvt<<<dim3((DWn * DHn / 4 + 255) / 256), dim3(256), 0, stream>>>(W2, W2b, DWn * DHn / 4);
  k_tcvt<<<dim3((HCn + 63) / 64, DHn / 64), dim3(256), 0, stream>>>(W1, W1t);
  // 4. Vs, Vd (c-split atomics)
  k_vsd<<<dim3(2 * Hn * VCC), dim3(256), 0, stream>>>(
      Wsrc, Wdst, att_src, att_dst, Vs, Vd);
  // 5. bc = W2@b1 + b2; fallback seeds out = bc + Hw (atomic GEMM accumulates)
  k_bc<<<dim3((DWn + 3) / 4), dim3(256), 0, stream>>>(W2, b1, b2, bc);
  if (!bigpath)
    k_initout<<<dim3((NWn * DWn / 4 + 255) / 256), dim3(256), 0, stream>>>(bc, Hw, out);
  // 6. Wc = W2b @ W1t^T via split-K MFMA (M=300, N=1800, K=2048, 8 splits)
  k_mfma<2><<<dim3((HCn + 127) / 128, (DWn + 127) / 128, 8), dim3(256), 0, stream>>>(
      W2b, W1t, WcP, DWn, HCn, DHn, DHn, DHn, HCp, nullptr, nullptr, 0);
  k_wc_reduce<<<dim3((DWn * HCp + 255) / 256), dim3(256), 0, stream>>>(WcP, Wcb);
  // 7. a_s = Hs @ Vs^T, a_d = Hw @ Vd^T
  k_rowdot<<<dim3((NSn + 3) / 4), dim3(256), Hn * DSn * sizeof(float), stream>>>(
      Hs, Vs, a_s, NSn, DSn);
  k_rowdot<<<dim3((NWn + 3) / 4), dim3(256), Hn * DWn * sizeof(float), stream>>>(
      Hw, Vd, a_d, NWn, DWn);
  // 8. xs = Hsb @ Wsrcb^T -> bf16  (M=10000, N=1800, K=640) via MFMA
  k_mfma<0><<<dim3((HCn + 127) / 128, (NSn + 127) / 128, 1), dim3(256), 0, stream>>>(
      Hsb, Wsrcb, xs, NSn, HCn, DSn, DSn, DSn, HCn, nullptr, nullptr, 0);
  // 9. per-edge alpha + segment max + degree
  k_alpha<<<dim3((NEn + 255) / 256), dim3(256), 0, stream>>>(
      s2w, flag, a_s, a_d, wgt, m_enc, deg);
  // 10. per-edge exp + segment sum (in-place on wgt)
  k_ex<<<dim3((NEn + 255) / 256), dim3(256), 0, stream>>>(s2w, flag, wgt, m_enc, den);
  // 11. CSR build
  k_scan1<<<dim3(NWB), dim3(256), 0, stream>>>(deg, offr, bsum);
  k_scan2<<<dim3(1), dim3(256), 0, stream>>>(bsum, boff, NWB);
  k_scan3<<<dim3(NWB), dim3(256), 0, stream>>>(offr, boff);
  k_fill<<<dim3((NEn + 255) / 256), dim3(256), 0, stream>>>(s2w, flag, offr, cur, eid);
  // 12. aggregate + final GEMM
  if (bigpath) {
    // single agg pass (50000 rows) + single M=50000 GEMM, direct store with
    // fused (+bc +Hw) epilogue — no atomics, no initout, one prologue/epilogue.
    k_agg<<<dim3(NWn), dim3(256), 0, stream>>>(
        s2w, flag, eid, offr, xs, wgt, den, bias_gat, aggc, 0);
    k_mfma<1><<<dim3((DWn + 127) / 128, (NWn + 127) / 128, 1), dim3(256), 0, stream>>>(
        aggc, Wcb, out, NWn, DWn, HCp, HCp, HCp, DWn, bc, Hw, 0);
  } else {
    for (int c = 0; c < NWn / CHUNK; ++c) {
      int rowbase = c * CHUNK;
      k_agg<<<dim3(CHUNK), dim3(256), 0, stream>>>(
          s2w, flag, eid, offr, xs, wgt, den, bias_gat, aggc, rowbase);
      k_mfma<3><<<dim3((DWn + 127) / 128, (CHUNK + 127) / 128, 3), dim3(256), 0, stream>>>(
          aggc, Wcb, out, CHUNK, DWn, HCp, HCp, HCp, DWn, nullptr, nullptr, rowbase);
    }
  }
}